// Round 7
// baseline (883.348 us; speedup 1.0000x reference)
//
#include <hip/hip_runtime.h>
#include <hip/hip_cooperative_groups.h>
#include <math.h>

namespace cg = cooperative_groups;

#define NNODES 10000
#define BATCH  32
#define DDIM   512
#define KSEL   5000
#define EPSV   1e-8f

// ---- cooperative pipeline geometry ----
#define TPB        512
#define NBLK       256                 // <= CU count: co-residency guaranteed at 1 blk/CU
#define CHUNKB     8                   // batches per chunk
#define NCHUNK     (BATCH / CHUNKB)    // 4
#define NSTAGE     (NCHUNK + 2)        // 6
#define SCORE_BLKS 216
#define SEL_BLK0   216                 // 8 selector blocks (216..223)
#define POOL_BLK0  224                 // 32 pool blocks   (224..255)
#define SPAN       250
#define IPCH       (CHUNKB * KSEL / SPAN)  // 160 pool items per chunk
#define SCORE_WV   (SCORE_BLKS * 8)    // 1728 score waves
#define CQUADS     (CHUNKB * NNODES / 4)   // 20000 node-quads per chunk
#define SM_BYTES   49664

// ---- fallback geometry (proven ~183 us path) ----
#define FSPAN      125

// Monotone map: float ordering -> unsigned ordering
__device__ __forceinline__ unsigned mapf(float f) {
    unsigned u = __float_as_uint(f);
    return (u & 0x80000000u) ? ~u : (u | 0x80000000u);
}

// ================= shared radix machinery (NT = threads) =================
template <int NT>
__device__ void radix_level(const float* __restrict__ s, unsigned* hist, unsigned* segsum,
                            unsigned prefix, int prefshift, int shift, int nbins,
                            unsigned k, unsigned* res, int tid) {
    for (int i = tid; i < nbins; i += NT) hist[i] = 0;
    __syncthreads();
    for (int i = tid; i < NNODES; i += NT) {
        unsigned u = mapf(s[i]);
        bool cand = (prefshift >= 32) || ((u >> prefshift) == prefix);
        if (cand) atomicAdd(&hist[(u >> shift) & (unsigned)(nbins - 1)], 1u);
    }
    __syncthreads();
    int nseg = nbins >> 5;
    if (tid < nseg) {
        unsigned ssum = 0;
        for (int j = 0; j < 32; j++) ssum += hist[(tid << 5) + j];
        segsum[tid] = ssum;
    }
    __syncthreads();
    if (tid == 0) {
        unsigned cum = 0;
        int seg = 0;
        for (int i = nseg - 1; i >= 0; i--) {
            if (cum + segsum[i] >= k) { seg = i; break; }
            cum += segsum[i];
        }
        int bin = seg << 5;
        for (int j = 31; j >= 0; j--) {
            unsigned h = hist[(seg << 5) + j];
            if (cum + h >= k) { bin = (seg << 5) + j; break; }
            cum += h;
        }
        res[0] = (unsigned)bin;
        res[1] = cum;
    }
    __syncthreads();
}

// Select core (NT threads, NW = NT/64 waves): stats, 3-level radix K-th largest,
// loss, compacted (idx,wt); zeroes this batch's pooled slice.
template <int NT>
__device__ void select_core(int b, const float* __restrict__ raw,
                            int* __restrict__ sel_idx, float* __restrict__ sel_wt,
                            float* __restrict__ out_pooled, float* __restrict__ loss_out,
                            char* SM) {
    const int NW = NT / 64;
    float*    s      = (float*)SM;                 // 40000 B
    unsigned* hist   = (unsigned*)(SM + 40000);    // 8192 B
    unsigned* segsum = (unsigned*)(SM + 48192);    // 256 B
    float*    fredA  = (float*)(SM + 48448);       // NW
    float*    fredB  = (float*)(SM + 48512);       // NW
    unsigned* eq_idx = (unsigned*)(SM + 48576);    // 512 B
    int*      icnt   = (int*)(SM + 49088);         // [0]=eq [1]=sel
    float*    fb     = (float*)(SM + 49096);
    unsigned* res    = (unsigned*)(SM + 49104);

    const int tid = threadIdx.x;
    const int lane = tid & 63, wid = tid >> 6;
    const float* rb = raw + (size_t)b * NNODES;
    int* sib = sel_idx + (size_t)b * KSEL;
    float* swb = sel_wt + (size_t)b * KSEL;

    for (int i = tid; i < DDIM; i += NT) out_pooled[(size_t)b * DDIM + i] = 0.f;

    float sum = 0.f, sumsq = 0.f;
    for (int i = tid; i < NNODES; i += NT) {
        float v = rb[i];
        s[i] = v;
        sum += v; sumsq += v * v;
    }
    for (int off = 32; off > 0; off >>= 1) {
        sum += __shfl_down(sum, off);
        sumsq += __shfl_down(sumsq, off);
    }
    if (lane == 0) { fredA[wid] = sum; fredB[wid] = sumsq; }
    if (tid == 0) { icnt[0] = 0; icnt[1] = 0; }
    __syncthreads();
    if (tid == 0) {
        float ts = 0.f, tq = 0.f;
        for (int i = 0; i < NW; i++) { ts += fredA[i]; tq += fredB[i]; }
        float mu = ts / (float)NNODES;
        float var = tq / (float)NNODES - mu * mu;
        fb[0] = mu; fb[1] = 1.f / (sqrtf(fmaxf(var, 0.f)) + EPSV);
    }
    __syncthreads();
    const float mu = fb[0], inv = fb[1];

    radix_level<NT>(s, hist, segsum, 0u, 32, 21, 2048, (unsigned)KSEL, res, tid);
    unsigned t1 = res[0];
    unsigned cg = res[1];
    unsigned k1 = (unsigned)KSEL - cg;
    radix_level<NT>(s, hist, segsum, t1, 21, 10, 2048, k1, res, tid);
    unsigned t2 = res[0];
    cg += res[1];
    unsigned k2 = k1 - res[1];
    unsigned p2 = (t1 << 11) | t2;
    radix_level<NT>(s, hist, segsum, p2, 10, 0, 1024, k2, res, tid);
    unsigned t3 = res[0];
    cg += res[1];
    const unsigned tu = (p2 << 10) | t3;
    const unsigned count_gt = cg;

    float l = 0.f;
    for (int i = tid; i < NNODES; i += NT) {
        float v = s[i];
        unsigned m = mapf(v);
        float z = (v - mu) * inv;
        float sig = 1.f / (1.f + expf(-z));
        if (m > tu) {
            l += logf(sig + EPSV);
            int p = atomicAdd(&icnt[1], 1);
            sib[p] = i; swb[p] = sig;
        } else if (m < tu) {
            l += logf(1.f - sig + EPSV);
        } else {
            int p = atomicAdd(&icnt[0], 1);
            if (p < 128) eq_idx[p] = (unsigned)i;
        }
    }
    for (int off = 32; off > 0; off >>= 1) l += __shfl_down(l, off);
    if (lane == 0) fredA[wid] = l;
    __syncthreads();
    if (tid == 0) {
        float tl = 0.f;
        for (int i = 0; i < NW; i++) tl += fredA[i];
        int ce = icnt[0];
        int stored = ce > 128 ? 128 : ce;
        for (int i = 1; i < stored; i++) {  // ties ascending (jax prefers lower idx)
            unsigned key = eq_idx[i]; int j = i - 1;
            while (j >= 0 && eq_idx[j] > key) { eq_idx[j + 1] = eq_idx[j]; j--; }
            eq_idx[j + 1] = key;
        }
        int ne = KSEL - (int)count_gt;
        int sc = icnt[1];
        for (int p = 0; p < stored; p++) {
            unsigned idx = eq_idx[p];
            float v = s[idx];
            float z = (v - mu) * inv;
            float sig = 1.f / (1.f + expf(-z));
            if (p < ne) { tl += logf(sig + EPSV); sib[sc] = (int)idx; swb[sc] = sig; sc++; }
            else        { tl += logf(1.f - sig + EPSV); }
        }
        if (ce > stored) {  // pathological mass-tie fallback
            float v = s[eq_idx[0]];
            float z = (v - mu) * inv;
            float sig = 1.f / (1.f + expf(-z));
            int extra_sel = ne - stored; if (extra_sel < 0) extra_sel = 0;
            for (int p = 0; p < extra_sel; p++) { sib[sc] = (int)eq_idx[0]; swb[sc] = sig; sc++; }
            tl += (float)((ce - stored) - extra_sel) * logf(1.f - sig + EPSV);
        }
        atomicAdd(loss_out, (-tl / (float)NNODES) / (float)BATCH);
    }
    __syncthreads();
}

// Pool one 250-entry item of batch b (512 thr = 4 subgroups x 128)
__device__ void do_pool(int b, int e0, const float* __restrict__ x,
                        const int* __restrict__ sel_idx, const float* __restrict__ sel_wt,
                        float* __restrict__ out, char* SM) {
    int*    sidx = (int*)SM;             // 1000 B
    float*  swt  = (float*)(SM + 1024);  // 1000 B
    float4* red  = (float4*)(SM + 2048); // 8192 B
    const int tid = threadIdx.x;
    const int sub = tid >> 7, l = tid & 127;
    __syncthreads();
    if (tid < SPAN) {
        sidx[tid] = sel_idx[(size_t)b * KSEL + e0 + tid];
        swt[tid]  = sel_wt[(size_t)b * KSEL + e0 + tid];
    }
    __syncthreads();
    const float4* xb = (const float4*)x + (size_t)b * NNODES * (DDIM / 4);
    float ax = 0.f, ay = 0.f, az = 0.f, aw = 0.f;
    for (int rr = sub; rr < SPAN; rr += 4) {
        int n = sidx[rr];
        float wt = swt[rr];
        float4 xv = xb[(size_t)n * (DDIM / 4) + l];
        ax += xv.x * wt; ay += xv.y * wt;
        az += xv.z * wt; aw += xv.w * wt;
    }
    float4 a; a.x = ax; a.y = ay; a.z = az; a.w = aw;
    red[sub * 128 + l] = a;
    __syncthreads();
    if (sub == 0) {
        float4 t = red[l], t1 = red[128 + l], t2 = red[256 + l], t3 = red[384 + l];
        t.x += t1.x + t2.x + t3.x; t.y += t1.y + t2.y + t3.y;
        t.z += t1.z + t2.z + t3.z; t.w += t1.w + t2.w + t3.w;
        const float sc = 1.f / (float)KSEL;
        float* o = out + b * DDIM + l * 4;
        atomicAdd(o + 0, t.x * sc); atomicAdd(o + 1, t.y * sc);
        atomicAdd(o + 2, t.z * sc); atomicAdd(o + 3, t.w * sc);
    }
    __syncthreads();
}

// ================= cooperative mega-kernel =================
// stage s: score(chunk s) || select(chunk s-1) || pool(chunk s-2); grid.sync between.
__global__ __launch_bounds__(TPB) void mega_kernel(
        const float* __restrict__ x, const float* __restrict__ v,
        float* __restrict__ raw, int* __restrict__ sel_idx, float* __restrict__ sel_wt,
        float* __restrict__ out, float* __restrict__ loss_out) {
    __shared__ __align__(16) char SM[SM_BYTES];
    cg::grid_group grid = cg::this_grid();
    const int tid = threadIdx.x;
    const int bid = blockIdx.x;
    const int lane = tid & 63, wv = tid >> 6;

    // w = v/||v|| per block (fixed reduction order -> bit-identical), kept in regs
    {
        float* wsh = (float*)SM;
        float* red = (float*)(SM + 2048);
        float vv = v[tid];
        float sq = vv * vv;
        for (int off = 32; off > 0; off >>= 1) sq += __shfl_down(sq, off);
        if (lane == 0) red[wv] = sq;
        __syncthreads();
        float nrm = sqrtf(red[0] + red[1] + red[2] + red[3] +
                          red[4] + red[5] + red[6] + red[7]) + EPSV;
        wsh[tid] = vv / nrm;
        __syncthreads();
    }
    const float4* wp = (const float4*)SM;
    const float4 wA = wp[lane], wB = wp[lane + 64];
    __syncthreads();  // w in regs everywhere; SM free for stage use

    for (int stage = 0; stage < NSTAGE; ++stage) {
        if (bid < SCORE_BLKS) {
            if (stage < NCHUNK) {
                const int cbase = stage * (CHUNKB * NNODES);  // first node of chunk
                for (int q = bid * 8 + wv; q < CQUADS; q += SCORE_WV) {
                    const int node = cbase + q * 4;
                    const float4* xp = (const float4*)(x + (size_t)node * DDIM);
                    float4 a0 = xp[lane],       a1 = xp[lane + 64];
                    float4 b0 = xp[128 + lane], b1 = xp[128 + lane + 64];
                    float4 c0 = xp[256 + lane], c1 = xp[256 + lane + 64];
                    float4 e0 = xp[384 + lane], e1 = xp[384 + lane + 64];
                    float d0 = a0.x * wA.x + a0.y * wA.y + a0.z * wA.z + a0.w * wA.w
                             + a1.x * wB.x + a1.y * wB.y + a1.z * wB.z + a1.w * wB.w;
                    float d1 = b0.x * wA.x + b0.y * wA.y + b0.z * wA.z + b0.w * wA.w
                             + b1.x * wB.x + b1.y * wB.y + b1.z * wB.z + b1.w * wB.w;
                    float d2 = c0.x * wA.x + c0.y * wA.y + c0.z * wA.z + c0.w * wA.w
                             + c1.x * wB.x + c1.y * wB.y + c1.z * wB.z + c1.w * wB.w;
                    float d3 = e0.x * wA.x + e0.y * wA.y + e0.z * wA.z + e0.w * wA.w
                             + e1.x * wB.x + e1.y * wB.y + e1.z * wB.z + e1.w * wB.w;
                    for (int off = 32; off > 0; off >>= 1) {
                        d0 += __shfl_down(d0, off);
                        d1 += __shfl_down(d1, off);
                        d2 += __shfl_down(d2, off);
                        d3 += __shfl_down(d3, off);
                    }
                    if (lane == 0) {
                        float4 r; r.x = d0; r.y = d1; r.z = d2; r.w = d3;
                        *(float4*)(raw + node) = r;
                    }
                }
            }
        } else if (bid < POOL_BLK0) {
            const int c = stage - 1;
            if (stage == 0) {
                if (bid == SEL_BLK0 && tid == 0) loss_out[0] = 0.f;
            } else if (c < NCHUNK) {
                select_core<TPB>(c * CHUNKB + (bid - SEL_BLK0), raw, sel_idx, sel_wt,
                                 out, loss_out, SM);
            }
        } else {
            const int c = stage - 2;
            if (c >= 0 && c < NCHUNK) {
                for (int j = bid - POOL_BLK0; j < IPCH; j += NBLK - POOL_BLK0) {
                    do_pool(c * CHUNKB + j / (IPCH / CHUNKB),
                            (j % (IPCH / CHUNKB)) * SPAN, x, sel_idx, sel_wt, out, SM);
                }
            }
        }
        grid.sync();
    }
}

// ================= fallback path (proven ~183 us) =================
__global__ __launch_bounds__(256) void fb_score_kernel(const float* __restrict__ x,
                                                       const float* __restrict__ v,
                                                       float* __restrict__ raw,
                                                       float* __restrict__ loss_out) {
    __shared__ float wsh[DDIM];
    __shared__ float red[4];
    const int tid = threadIdx.x;
    const int lane = tid & 63, wv = tid >> 6;

    float v1 = v[tid], v2 = v[tid + 256];
    float sq = v1 * v1 + v2 * v2;
    for (int off = 32; off > 0; off >>= 1) sq += __shfl_down(sq, off);
    if (lane == 0) red[wv] = sq;
    __syncthreads();
    float nrm = sqrtf(red[0] + red[1] + red[2] + red[3]) + EPSV;
    wsh[tid] = v1 / nrm;
    wsh[tid + 256] = v2 / nrm;
    __syncthreads();
    if (blockIdx.x == 0 && tid == 0) loss_out[0] = 0.f;

    const float4* wp = (const float4*)wsh;
    const float4 wA = wp[lane], wB = wp[lane + 64];

    const int base = blockIdx.x * 16 + wv * 4;
    const float4* xp = (const float4*)(x + (size_t)base * DDIM);

    float4 a0 = xp[0 * 128 + lane], a1 = xp[0 * 128 + lane + 64];
    float4 b0 = xp[1 * 128 + lane], b1 = xp[1 * 128 + lane + 64];
    float4 c0 = xp[2 * 128 + lane], c1 = xp[2 * 128 + lane + 64];
    float4 e0 = xp[3 * 128 + lane], e1 = xp[3 * 128 + lane + 64];

    float d0 = a0.x * wA.x + a0.y * wA.y + a0.z * wA.z + a0.w * wA.w
             + a1.x * wB.x + a1.y * wB.y + a1.z * wB.z + a1.w * wB.w;
    float d1 = b0.x * wA.x + b0.y * wA.y + b0.z * wA.z + b0.w * wA.w
             + b1.x * wB.x + b1.y * wB.y + b1.z * wB.z + b1.w * wB.w;
    float d2 = c0.x * wA.x + c0.y * wA.y + c0.z * wA.z + c0.w * wA.w
             + c1.x * wB.x + c1.y * wB.y + c1.z * wB.z + c1.w * wB.w;
    float d3 = e0.x * wA.x + e0.y * wA.y + e0.z * wA.z + e0.w * wA.w
             + e1.x * wB.x + e1.y * wB.y + e1.z * wB.z + e1.w * wB.w;

    for (int off = 32; off > 0; off >>= 1) {
        d0 += __shfl_down(d0, off);
        d1 += __shfl_down(d1, off);
        d2 += __shfl_down(d2, off);
        d3 += __shfl_down(d3, off);
    }
    if (lane == 0) {
        float4 r; r.x = d0; r.y = d1; r.z = d2; r.w = d3;
        *(float4*)(raw + base) = r;
    }
}

__global__ __launch_bounds__(1024) void fb_select_kernel(const float* __restrict__ raw,
                                                         int* __restrict__ sel_idx,
                                                         float* __restrict__ sel_wt,
                                                         float* __restrict__ out_pooled,
                                                         float* __restrict__ loss_out) {
    __shared__ __align__(16) char SM[SM_BYTES];
    select_core<1024>(blockIdx.x, raw, sel_idx, sel_wt, out_pooled, loss_out, SM);
}

__global__ __launch_bounds__(128) void fb_pool_kernel(const float* __restrict__ x,
                                                      const int* __restrict__ sel_idx,
                                                      const float* __restrict__ sel_wt,
                                                      float* __restrict__ out) {
    __shared__ int sidx[FSPAN];
    __shared__ float swt[FSPAN];
    const int spans = KSEL / FSPAN;  // 40
    const int b = blockIdx.x / spans;
    const int sp = blockIdx.x % spans;
    const int e0 = sp * FSPAN;
    const int tid = threadIdx.x;
    const int* ib = sel_idx + (size_t)b * KSEL + e0;
    const float* wp = sel_wt + (size_t)b * KSEL + e0;
    for (int i = tid; i < FSPAN; i += 128) { sidx[i] = ib[i]; swt[i] = wp[i]; }
    __syncthreads();
    const float4* xb = (const float4*)x + (size_t)b * NNODES * (DDIM / 4);
    float ax = 0.f, ay = 0.f, az = 0.f, aw = 0.f;
    for (int e = 0; e < FSPAN; e++) {
        int n = sidx[e];
        float wt = swt[e];
        float4 xv = xb[(size_t)n * (DDIM / 4) + tid];
        ax += xv.x * wt; ay += xv.y * wt;
        az += xv.z * wt; aw += xv.w * wt;
    }
    const float scale = 1.f / (float)KSEL;
    float* o = out + b * DDIM + tid * 4;
    atomicAdd(o + 0, ax * scale);
    atomicAdd(o + 1, ay * scale);
    atomicAdd(o + 2, az * scale);
    atomicAdd(o + 3, aw * scale);
}

extern "C" void kernel_launch(void* const* d_in, const int* in_sizes, int n_in,
                              void* d_out, int out_size, void* d_ws, size_t ws_size,
                              hipStream_t stream) {
    const float* x = (const float*)d_in[0];   // (B*N, D) fp32
    const float* v = (const float*)d_in[1];   // (D, 1) fp32
    float* out = (float*)d_out;               // pooled (B*D) then loss (1)

    float* raw     = (float*)d_ws;                     // B*N
    int*   sel_idx = (int*)(raw + BATCH * NNODES);     // B*K
    float* sel_wt  = (float*)(sel_idx + BATCH * KSEL); // B*K
    float* lossp   = out + BATCH * DDIM;

    void* args[] = { (void*)&x, (void*)&v, (void*)&raw, (void*)&sel_idx,
                     (void*)&sel_wt, (void*)&out, (void*)&lossp };
    hipError_t e = hipLaunchCooperativeKernel((void*)mega_kernel, dim3(NBLK), dim3(TPB),
                                              args, 0, stream);
    if (e != hipSuccess) {
        (void)hipGetLastError();  // clear sticky state; use proven 3-kernel path
        int total = BATCH * NNODES;
        fb_score_kernel<<<total / 16, 256, 0, stream>>>(x, v, raw, lossp);
        fb_select_kernel<<<BATCH, 1024, 0, stream>>>(raw, sel_idx, sel_wt, out, lossp);
        fb_pool_kernel<<<BATCH * (KSEL / FSPAN), 128, 0, stream>>>(x, sel_idx, sel_wt, out);
    }
}

// Round 9
// 193.681 us; speedup vs baseline: 4.5608x; 4.5608x over previous
//
#include <hip/hip_runtime.h>
#include <math.h>

#define NNODES 10000
#define BATCH  32
#define DDIM   512
#define KSEL   5000
#define EPSV   1e-8f
#define SPAN   125
#define RPT    10      // contiguous nodes per select thread (1000 threads cover 10000)

// Monotone map: float ordering -> unsigned ordering
__device__ __forceinline__ unsigned mapf(float f) {
    unsigned u = __float_as_uint(f);
    return (u & 0x80000000u) ? ~u : (u | 0x80000000u);
}

// K0: w = v/||v||, zero loss slot
__global__ __launch_bounds__(512) void prep_kernel(const float* __restrict__ v,
                                                   float* __restrict__ w,
                                                   float* __restrict__ loss_out) {
    __shared__ float red[8];
    __shared__ float nrm;
    int tid = threadIdx.x;
    float val = v[tid];
    float sq = val * val;
    for (int off = 32; off > 0; off >>= 1) sq += __shfl_down(sq, off);
    if ((tid & 63) == 0) red[tid >> 6] = sq;
    __syncthreads();
    if (tid == 0) {
        float s = 0.f;
        for (int i = 0; i < 8; i++) s += red[i];
        nrm = sqrtf(s) + EPSV;
        *loss_out = 0.f;
    }
    __syncthreads();
    w[tid] = val / nrm;
}

// K1: score. 256 thr = 4 waves/block; each wave scores 4 consecutive nodes
// with w held in registers (loaded once from global, L1/L2-broadcast).
__global__ __launch_bounds__(256) void score_kernel(const float* __restrict__ x,
                                                    const float* __restrict__ w,
                                                    float* __restrict__ raw) {
    const int tid = threadIdx.x;
    const int lane = tid & 63, wv = tid >> 6;

    const float4* wp = (const float4*)w;
    const float4 wA = wp[lane], wB = wp[lane + 64];

    const int base = blockIdx.x * 16 + wv * 4;  // first of this wave's 4 nodes
    const float4* xp = (const float4*)(x + (size_t)base * DDIM);

    float4 a0 = xp[0 * 128 + lane], a1 = xp[0 * 128 + lane + 64];
    float4 b0 = xp[1 * 128 + lane], b1 = xp[1 * 128 + lane + 64];
    float4 c0 = xp[2 * 128 + lane], c1 = xp[2 * 128 + lane + 64];
    float4 e0 = xp[3 * 128 + lane], e1 = xp[3 * 128 + lane + 64];

    float d0 = a0.x * wA.x + a0.y * wA.y + a0.z * wA.z + a0.w * wA.w
             + a1.x * wB.x + a1.y * wB.y + a1.z * wB.z + a1.w * wB.w;
    float d1 = b0.x * wA.x + b0.y * wA.y + b0.z * wA.z + b0.w * wA.w
             + b1.x * wB.x + b1.y * wB.y + b1.z * wB.z + b1.w * wB.w;
    float d2 = c0.x * wA.x + c0.y * wA.y + c0.z * wA.z + c0.w * wA.w
             + c1.x * wB.x + c1.y * wB.y + c1.z * wB.z + c1.w * wB.w;
    float d3 = e0.x * wA.x + e0.y * wA.y + e0.z * wA.z + e0.w * wA.w
             + e1.x * wB.x + e1.y * wB.y + e1.z * wB.z + e1.w * wB.w;

    for (int off = 32; off > 0; off >>= 1) {
        d0 += __shfl_down(d0, off);
        d1 += __shfl_down(d1, off);
        d2 += __shfl_down(d2, off);
        d3 += __shfl_down(d3, off);
    }
    if (lane == 0) {
        float4 r; r.x = d0; r.y = d1; r.z = d2; r.w = d3;
        *(float4*)(raw + base) = r;
    }
}

// One radix level: histogram candidates (prefix-matched) into nbins on bits
// [shift .. shift+log2(nbins)); res[0]=bin of k-th largest, res[1]=count above.
__device__ void radix_level(const float* __restrict__ s, unsigned* hist, unsigned* segsum,
                            unsigned prefix, int prefshift, int shift, int nbins,
                            unsigned k, unsigned* res, int tid) {
    for (int i = tid; i < nbins; i += 1024) hist[i] = 0;
    __syncthreads();
    for (int i = tid; i < NNODES; i += 1024) {
        unsigned u = mapf(s[i]);
        bool cand = (prefshift >= 32) || ((u >> prefshift) == prefix);
        if (cand) atomicAdd(&hist[(u >> shift) & (unsigned)(nbins - 1)], 1u);
    }
    __syncthreads();
    int nseg = nbins >> 5;
    if (tid < nseg) {
        unsigned ssum = 0;
        for (int j = 0; j < 32; j++) ssum += hist[(tid << 5) + j];
        segsum[tid] = ssum;
    }
    __syncthreads();
    if (tid == 0) {
        unsigned cum = 0;
        int seg = 0;
        for (int i = nseg - 1; i >= 0; i--) {
            if (cum + segsum[i] >= k) { seg = i; break; }
            cum += segsum[i];
        }
        int bin = seg << 5;
        for (int j = 31; j >= 0; j--) {
            unsigned h = hist[(seg << 5) + j];
            if (cum + h >= k) { bin = (seg << 5) + j; break; }
            cum += h;
        }
        res[0] = (unsigned)bin;
        res[1] = cum;
    }
    __syncthreads();
}

// K2: stats, radix K-th largest, loss, SORTED compacted (idx,wt) via prefix-sum.
// Each thread owns RPT contiguous nodes -> output list is globally index-sorted
// (pool then gathers rows in ascending address order). Zeroes pooled slice.
__global__ __launch_bounds__(1024) void select_kernel(const float* __restrict__ raw,
                                                      int* __restrict__ sel_idx,
                                                      float* __restrict__ sel_wt,
                                                      float* __restrict__ out_pooled,
                                                      float* __restrict__ loss_out) {
    __shared__ float s[NNODES];
    __shared__ unsigned hist[2048];
    __shared__ unsigned segsum[64];
    __shared__ float fredA[16], fredB[16];
    __shared__ unsigned wsum[16];
    __shared__ unsigned eq_idx[128];
    __shared__ int eq_cnt;
    __shared__ float fb[2];
    __shared__ unsigned res[2];

    const int tid = threadIdx.x;
    const int lane = tid & 63;
    const int wid = tid >> 6;
    const int b = blockIdx.x;
    const float* rb = raw + (size_t)b * NNODES;
    int* sib = sel_idx + (size_t)b * KSEL;
    float* swb = sel_wt + (size_t)b * KSEL;

    for (int i = tid; i < DDIM; i += 1024) out_pooled[(size_t)b * DDIM + i] = 0.f;

    // coalesced load + stats
    float sum = 0.f, sumsq = 0.f;
    for (int i = tid; i < NNODES; i += 1024) {
        float v = rb[i];
        s[i] = v;
        sum += v; sumsq += v * v;
    }
    for (int off = 32; off > 0; off >>= 1) {
        sum += __shfl_down(sum, off);
        sumsq += __shfl_down(sumsq, off);
    }
    if (lane == 0) { fredA[wid] = sum; fredB[wid] = sumsq; }
    if (tid == 0) eq_cnt = 0;
    __syncthreads();
    if (tid == 0) {
        float ts = 0.f, tq = 0.f;
        for (int i = 0; i < 16; i++) { ts += fredA[i]; tq += fredB[i]; }
        float mu = ts / (float)NNODES;
        float var = tq / (float)NNODES - mu * mu;
        fb[0] = mu; fb[1] = 1.f / (sqrtf(fmaxf(var, 0.f)) + EPSV);
    }
    __syncthreads();
    const float mu = fb[0], inv = fb[1];

    // 3-level radix select: bits [31:21], [20:10], [9:0]
    radix_level(s, hist, segsum, 0u, 32, 21, 2048, (unsigned)KSEL, res, tid);
    unsigned t1 = res[0];
    unsigned cg = res[1];
    unsigned k1 = (unsigned)KSEL - cg;
    radix_level(s, hist, segsum, t1, 21, 10, 2048, k1, res, tid);
    unsigned t2 = res[0];
    cg += res[1];
    unsigned k2 = k1 - res[1];
    unsigned p2 = (t1 << 11) | t2;
    radix_level(s, hist, segsum, p2, 10, 0, 1024, k2, res, tid);
    unsigned t3 = res[0];
    cg += res[1];
    const unsigned tu = (p2 << 10) | t3;
    const unsigned count_gt = cg;

    // per-thread contiguous range: count selected
    const int t0 = tid * RPT;
    unsigned cnt = 0;
    if (t0 < NNODES) {
        #pragma unroll
        for (int j = 0; j < RPT; j++) cnt += (mapf(s[t0 + j]) > tu) ? 1u : 0u;
    }
    // exclusive prefix across 1024 threads (wave scan + cross-wave scan)
    unsigned inc = cnt;
    for (int off = 1; off < 64; off <<= 1) {
        unsigned n = __shfl_up(inc, off);
        if (lane >= off) inc += n;
    }
    if (lane == 63) wsum[wid] = inc;
    __syncthreads();
    if (wid == 0) {
        unsigned vls = (lane < 16) ? wsum[lane] : 0u;
        for (int off = 1; off < 16; off <<= 1) {
            unsigned n = __shfl_up(vls, off);
            if (lane >= off) vls += n;
        }
        if (lane < 16) wsum[lane] = vls;
    }
    __syncthreads();
    unsigned bofs = (wid ? wsum[wid - 1] : 0u) + inc - cnt;

    // loss + sorted compaction; collect tied-at-threshold indices
    float l = 0.f;
    if (t0 < NNODES) {
        for (int j = 0; j < RPT; j++) {
            int i = t0 + j;
            float v = s[i];
            unsigned m = mapf(v);
            float z = (v - mu) * inv;
            float sig = 1.f / (1.f + expf(-z));
            if (m > tu) {
                l += logf(sig + EPSV);
                sib[bofs] = i; swb[bofs] = sig; bofs++;
            } else if (m < tu) {
                l += logf(1.f - sig + EPSV);
            } else {
                int p = atomicAdd(&eq_cnt, 1);
                if (p < 128) eq_idx[p] = (unsigned)i;
            }
        }
    }
    for (int off = 32; off > 0; off >>= 1) l += __shfl_down(l, off);
    if (lane == 0) fredA[wid] = l;
    __syncthreads();
    if (tid == 0) {
        float tl = 0.f;
        for (int i = 0; i < 16; i++) tl += fredA[i];
        int ce = eq_cnt;
        int stored = ce > 128 ? 128 : ce;
        for (int i = 1; i < stored; i++) {  // ties ascending (jax prefers lower idx)
            unsigned key = eq_idx[i]; int j = i - 1;
            while (j >= 0 && eq_idx[j] > key) { eq_idx[j + 1] = eq_idx[j]; j--; }
            eq_idx[j + 1] = key;
        }
        int ne = KSEL - (int)count_gt;
        int sc = (int)count_gt;  // selected writes filled [0, count_gt)
        for (int p = 0; p < stored; p++) {
            unsigned idx = eq_idx[p];
            float v = s[idx];
            float z = (v - mu) * inv;
            float sig = 1.f / (1.f + expf(-z));
            if (p < ne) { tl += logf(sig + EPSV); sib[sc] = (int)idx; swb[sc] = sig; sc++; }
            else        { tl += logf(1.f - sig + EPSV); }
        }
        if (ce > stored) {  // pathological mass-tie fallback
            float v = s[eq_idx[0]];
            float z = (v - mu) * inv;
            float sig = 1.f / (1.f + expf(-z));
            int extra_sel = ne - stored; if (extra_sel < 0) extra_sel = 0;
            for (int p = 0; p < extra_sel; p++) { sib[sc] = (int)eq_idx[0]; swb[sc] = sig; sc++; }
            tl += (float)((ce - stored) - extra_sel) * logf(1.f - sig + EPSV);
        }
        float loss_b = -tl / (float)NNODES;
        atomicAdd(loss_out, loss_b / (float)BATCH);
    }
}

// K3: pooled[b,:] += (1/K) * sum over a SPAN of the (sorted) selection list.
__global__ __launch_bounds__(128) void pool_kernel(const float* __restrict__ x,
                                                   const int* __restrict__ sel_idx,
                                                   const float* __restrict__ sel_wt,
                                                   float* __restrict__ out) {
    __shared__ int sidx[SPAN];
    __shared__ float swt[SPAN];
    const int spans = KSEL / SPAN;  // 40
    const int b = blockIdx.x / spans;
    const int sp = blockIdx.x % spans;
    const int e0 = sp * SPAN;
    const int tid = threadIdx.x;
    const int* ib = sel_idx + (size_t)b * KSEL + e0;
    const float* wp = sel_wt + (size_t)b * KSEL + e0;
    for (int i = tid; i < SPAN; i += 128) { sidx[i] = ib[i]; swt[i] = wp[i]; }
    __syncthreads();
    const float4* xb = (const float4*)x + (size_t)b * NNODES * (DDIM / 4);
    float ax = 0.f, ay = 0.f, az = 0.f, aw = 0.f;
    #pragma unroll 4
    for (int e = 0; e < SPAN; e++) {
        int n = sidx[e];
        float wt = swt[e];
        float4 xv = xb[(size_t)n * (DDIM / 4) + tid];
        ax += xv.x * wt; ay += xv.y * wt;
        az += xv.z * wt; aw += xv.w * wt;
    }
    const float scale = 1.f / (float)KSEL;
    float* o = out + b * DDIM + tid * 4;
    atomicAdd(o + 0, ax * scale);
    atomicAdd(o + 1, ay * scale);
    atomicAdd(o + 2, az * scale);
    atomicAdd(o + 3, aw * scale);
}

extern "C" void kernel_launch(void* const* d_in, const int* in_sizes, int n_in,
                              void* d_out, int out_size, void* d_ws, size_t ws_size,
                              hipStream_t stream) {
    const float* x = (const float*)d_in[0];   // (B*N, D) fp32
    const float* v = (const float*)d_in[1];   // (D, 1) fp32
    float* out = (float*)d_out;               // pooled (B*D) then loss (1)

    float* w       = (float*)d_ws;                     // 512
    float* raw     = w + DDIM;                         // B*N
    int*   sel_idx = (int*)(raw + BATCH * NNODES);     // B*K
    float* sel_wt  = (float*)(sel_idx + BATCH * KSEL); // B*K

    prep_kernel<<<1, DDIM, 0, stream>>>(v, w, out + BATCH * DDIM);
    int total = BATCH * NNODES;
    score_kernel<<<total / 16, 256, 0, stream>>>(x, w, raw);
    select_kernel<<<BATCH, 1024, 0, stream>>>(raw, sel_idx, sel_wt, out, out + BATCH * DDIM);
    pool_kernel<<<BATCH * (KSEL / SPAN), 128, 0, stream>>>(x, sel_idx, sel_wt, out);
}

// Round 10
// 182.806 us; speedup vs baseline: 4.8321x; 1.0595x over previous
//
#include <hip/hip_runtime.h>
#include <math.h>

#define NNODES 10000
#define BATCH  32
#define DDIM   512
#define KSEL   5000
#define EPSV   1e-8f
#define SPAN   125

// Monotone map: float ordering -> unsigned ordering
__device__ __forceinline__ unsigned mapf(float f) {
    unsigned u = __float_as_uint(f);
    return (u & 0x80000000u) ? ~u : (u | 0x80000000u);
}

// K0: w = v/||v||, zero loss slot
__global__ __launch_bounds__(512) void prep_kernel(const float* __restrict__ v,
                                                   float* __restrict__ w,
                                                   float* __restrict__ loss_out) {
    __shared__ float red[8];
    __shared__ float nrm;
    int tid = threadIdx.x;
    float val = v[tid];
    float sq = val * val;
    for (int off = 32; off > 0; off >>= 1) sq += __shfl_down(sq, off);
    if ((tid & 63) == 0) red[tid >> 6] = sq;
    __syncthreads();
    if (tid == 0) {
        float s = 0.f;
        for (int i = 0; i < 8; i++) s += red[i];
        nrm = sqrtf(s) + EPSV;
        *loss_out = 0.f;
    }
    __syncthreads();
    w[tid] = val / nrm;
}

// K1: raw[node] = dot(x[node,:], w)  -- one wave per node
__global__ __launch_bounds__(256) void score_kernel(const float* __restrict__ x,
                                                    const float* __restrict__ w,
                                                    float* __restrict__ raw, int total) {
    int wave = (blockIdx.x * 256 + threadIdx.x) >> 6;
    int lane = threadIdx.x & 63;
    if (wave >= total) return;
    const float4* xp = (const float4*)(x + (size_t)wave * DDIM);
    const float4* wp = (const float4*)w;
    float4 a0 = xp[lane], a1 = xp[lane + 64];
    float4 b0 = wp[lane], b1 = wp[lane + 64];
    float d = a0.x * b0.x + a0.y * b0.y + a0.z * b0.z + a0.w * b0.w
            + a1.x * b1.x + a1.y * b1.y + a1.z * b1.z + a1.w * b1.w;
    for (int off = 32; off > 0; off >>= 1) d += __shfl_down(d, off);
    if (lane == 0) raw[wave] = d;
}

// One radix level: histogram candidates (prefix-matched) into nbins on bits
// [shift .. shift+log2(nbins)), then find bin of the k-th largest.
// res[0] = bin index, res[1] = count strictly above that bin (within candidates).
__device__ void radix_level(const float* __restrict__ s, unsigned* hist, unsigned* segsum,
                            unsigned prefix, int prefshift, int shift, int nbins,
                            unsigned k, unsigned* res, int tid) {
    for (int i = tid; i < nbins; i += 1024) hist[i] = 0;
    __syncthreads();
    for (int i = tid; i < NNODES; i += 1024) {
        unsigned u = mapf(s[i]);
        bool cand = (prefshift >= 32) || ((u >> prefshift) == prefix);
        if (cand) atomicAdd(&hist[(u >> shift) & (unsigned)(nbins - 1)], 1u);
    }
    __syncthreads();
    int nseg = nbins >> 5;
    if (tid < nseg) {
        unsigned ssum = 0;
        for (int j = 0; j < 32; j++) ssum += hist[(tid << 5) + j];
        segsum[tid] = ssum;
    }
    __syncthreads();
    if (tid == 0) {
        unsigned cum = 0;
        int seg = 0;
        for (int i = nseg - 1; i >= 0; i--) {
            if (cum + segsum[i] >= k) { seg = i; break; }
            cum += segsum[i];
        }
        int bin = seg << 5;
        for (int j = 31; j >= 0; j--) {
            unsigned h = hist[(seg << 5) + j];
            if (cum + h >= k) { bin = (seg << 5) + j; break; }
            cum += h;
        }
        res[0] = (unsigned)bin;
        res[1] = cum;
    }
    __syncthreads();
}

// K2: per-batch stats, radix-select K-th largest, loss, compacted (idx, wt) list.
// Also zeroes this batch's pooled output slice.
__global__ __launch_bounds__(1024) void select_kernel(const float* __restrict__ raw,
                                                      int* __restrict__ sel_idx,
                                                      float* __restrict__ sel_wt,
                                                      float* __restrict__ out_pooled,
                                                      float* __restrict__ loss_out) {
    __shared__ float s[NNODES];
    __shared__ unsigned hist[2048];
    __shared__ unsigned segsum[64];
    __shared__ float fredA[16], fredB[16];
    __shared__ unsigned eq_idx[128];
    __shared__ int eq_cnt;
    __shared__ int sel_cnt;
    __shared__ float fb[2];
    __shared__ unsigned res[2];

    const int tid = threadIdx.x;
    const int lane = tid & 63;
    const int wid = tid >> 6;
    const int b = blockIdx.x;
    const float* rb = raw + (size_t)b * NNODES;
    int* sib = sel_idx + (size_t)b * KSEL;
    float* swb = sel_wt + (size_t)b * KSEL;

    // zero this batch's pooled slice (pool kernel atomically accumulates later)
    for (int i = tid; i < DDIM; i += 1024) out_pooled[(size_t)b * DDIM + i] = 0.f;

    float sum = 0.f, sumsq = 0.f;
    for (int i = tid; i < NNODES; i += 1024) {
        float v = rb[i];
        s[i] = v;
        sum += v; sumsq += v * v;
    }
    for (int off = 32; off > 0; off >>= 1) {
        sum += __shfl_down(sum, off);
        sumsq += __shfl_down(sumsq, off);
    }
    if (lane == 0) { fredA[wid] = sum; fredB[wid] = sumsq; }
    if (tid == 0) { eq_cnt = 0; sel_cnt = 0; }
    __syncthreads();
    if (tid == 0) {
        float ts = 0.f, tq = 0.f;
        for (int i = 0; i < 16; i++) { ts += fredA[i]; tq += fredB[i]; }
        float mu = ts / (float)NNODES;
        float var = tq / (float)NNODES - mu * mu;
        float sd = sqrtf(fmaxf(var, 0.f));
        fb[0] = mu; fb[1] = 1.f / (sd + EPSV);
    }
    __syncthreads();
    const float mu = fb[0], inv = fb[1];

    // 3-level radix select: bits [31:21], [20:10], [9:0]
    radix_level(s, hist, segsum, 0u, 32, 21, 2048, (unsigned)KSEL, res, tid);
    unsigned t1 = res[0];
    unsigned cg = res[1];
    unsigned k1 = (unsigned)KSEL - cg;
    radix_level(s, hist, segsum, t1, 21, 10, 2048, k1, res, tid);
    unsigned t2 = res[0];
    cg += res[1];
    unsigned k2 = k1 - res[1];
    unsigned p2 = (t1 << 11) | t2;
    radix_level(s, hist, segsum, p2, 10, 0, 1024, k2, res, tid);
    unsigned t3 = res[0];
    cg += res[1];
    const unsigned tu = (p2 << 10) | t3;
    const unsigned count_gt = cg;

    // loss + compaction; collect tied-at-threshold indices
    float l = 0.f;
    for (int i = tid; i < NNODES; i += 1024) {
        float v = s[i];
        unsigned m = mapf(v);
        float z = (v - mu) * inv;
        float sig = 1.f / (1.f + expf(-z));
        if (m > tu) {
            l += logf(sig + EPSV);
            int p = atomicAdd(&sel_cnt, 1);
            sib[p] = i; swb[p] = sig;
        } else if (m < tu) {
            l += logf(1.f - sig + EPSV);
        } else {
            int p = atomicAdd(&eq_cnt, 1);
            if (p < 128) eq_idx[p] = (unsigned)i;
        }
    }
    for (int off = 32; off > 0; off >>= 1) l += __shfl_down(l, off);
    if (lane == 0) fredA[wid] = l;
    __syncthreads();
    if (tid == 0) {
        float tl = 0.f;
        for (int i = 0; i < 16; i++) tl += fredA[i];
        int ce = eq_cnt;
        int stored = ce > 128 ? 128 : ce;
        // sort tied indices ascending (jax top_k prefers lower index)
        for (int i = 1; i < stored; i++) {
            unsigned key = eq_idx[i]; int j = i - 1;
            while (j >= 0 && eq_idx[j] > key) { eq_idx[j + 1] = eq_idx[j]; j--; }
            eq_idx[j + 1] = key;
        }
        int ne = KSEL - (int)count_gt;  // ties that enter the top-k
        int sc = sel_cnt;
        for (int p = 0; p < stored; p++) {
            unsigned idx = eq_idx[p];
            float v = s[idx];
            float z = (v - mu) * inv;
            float sig = 1.f / (1.f + expf(-z));
            if (p < ne) { tl += logf(sig + EPSV); sib[sc] = (int)idx; swb[sc] = sig; sc++; }
            else        { tl += logf(1.f - sig + EPSV); }
        }
        if (ce > stored) {  // pathological mass-tie fallback (never hit for random data)
            float v = s[eq_idx[0]];
            float z = (v - mu) * inv;
            float sig = 1.f / (1.f + expf(-z));
            int extra_sel = ne - stored; if (extra_sel < 0) extra_sel = 0;
            for (int p = 0; p < extra_sel; p++) { sib[sc] = (int)eq_idx[0]; swb[sc] = sig; sc++; }
            int rest = (ce - stored) - extra_sel;
            tl += (float)rest * logf(1.f - sig + EPSV);
        }
        float loss_b = -tl / (float)NNODES;
        atomicAdd(loss_out, loss_b / (float)BATCH);
    }
}

// K3: pooled[b,:] += (1/K) * sum over a SPAN of the compacted selection list
__global__ __launch_bounds__(128) void pool_kernel(const float* __restrict__ x,
                                                   const int* __restrict__ sel_idx,
                                                   const float* __restrict__ sel_wt,
                                                   float* __restrict__ out) {
    __shared__ int sidx[SPAN];
    __shared__ float swt[SPAN];
    const int spans = KSEL / SPAN;  // 40
    const int b = blockIdx.x / spans;
    const int sp = blockIdx.x % spans;
    const int e0 = sp * SPAN;
    const int tid = threadIdx.x;
    const int* ib = sel_idx + (size_t)b * KSEL + e0;
    const float* wp = sel_wt + (size_t)b * KSEL + e0;
    for (int i = tid; i < SPAN; i += 128) { sidx[i] = ib[i]; swt[i] = wp[i]; }
    __syncthreads();
    const float4* xb = (const float4*)x + (size_t)b * NNODES * (DDIM / 4);
    float4 acc = {0.f, 0.f, 0.f, 0.f};
    for (int e = 0; e < SPAN; e++) {
        int n = sidx[e];
        float wt = swt[e];
        float4 xv = xb[(size_t)n * (DDIM / 4) + tid];
        acc.x += xv.x * wt; acc.y += xv.y * wt;
        acc.z += xv.z * wt; acc.w += xv.w * wt;
    }
    const float scale = 1.f / (float)KSEL;
    float* o = out + b * DDIM + tid * 4;
    atomicAdd(o + 0, acc.x * scale);
    atomicAdd(o + 1, acc.y * scale);
    atomicAdd(o + 2, acc.z * scale);
    atomicAdd(o + 3, acc.w * scale);
}

extern "C" void kernel_launch(void* const* d_in, const int* in_sizes, int n_in,
                              void* d_out, int out_size, void* d_ws, size_t ws_size,
                              hipStream_t stream) {
    const float* x = (const float*)d_in[0];   // (B*N, D) fp32
    const float* v = (const float*)d_in[1];   // (D, 1) fp32
    float* out = (float*)d_out;               // pooled (B*D) then loss (1)

    float* w       = (float*)d_ws;                    // 512
    float* raw     = w + DDIM;                        // B*N
    int*   sel_idx = (int*)(raw + BATCH * NNODES);    // B*K
    float* sel_wt  = (float*)(sel_idx + BATCH * KSEL);// B*K

    prep_kernel<<<1, DDIM, 0, stream>>>(v, w, out + BATCH * DDIM);
    int total = BATCH * NNODES;
    score_kernel<<<total / 4, 256, 0, stream>>>(x, w, raw, total);
    select_kernel<<<BATCH, 1024, 0, stream>>>(raw, sel_idx, sel_wt, out, out + BATCH * DDIM);
    pool_kernel<<<BATCH * (KSEL / SPAN), 128, 0, stream>>>(x, sel_idx, sel_wt, out);
}